// Round 17
// baseline (429.695 us; speedup 1.0000x reference)
//
#include <hip/hip_runtime.h>
#include <hip/hip_bf16.h>
#include <math.h>

typedef unsigned int u32;
typedef short bf16x8 __attribute__((ext_vector_type(8)));
typedef float f32x4 __attribute__((ext_vector_type(4)));
typedef u32 u32x4 __attribute__((ext_vector_type(4)));

__device__ __forceinline__ float bf2f(short s) {
    u32 u = ((u32)(unsigned short)s) << 16;
    return __builtin_bit_cast(float, u);
}
__device__ __forceinline__ short f2bf(float f) {
    u32 u = __builtin_bit_cast(u32, f);
    u32 r = u + 0x7fffu + ((u >> 16) & 1u);
    return (short)(r >> 16);
}
__device__ __forceinline__ float fast_log2(float x) {
    float r; asm volatile("v_log_f32 %0, %1" : "=v"(r) : "v"(x)); return r;
}
__device__ __forceinline__ float fast_exp2(float x) {
    float r; asm volatile("v_exp_f32 %0, %1" : "=v"(r) : "v"(x)); return r;
}
// async global->LDS, 16B per lane; lds base must be wave-uniform
__device__ __forceinline__ void gload_lds16(const short* g, short* lds) {
    __builtin_amdgcn_global_load_lds(
        (const __attribute__((address_space(1))) u32*)g,
        (__attribute__((address_space(3))) u32*)lds, 16, 0, 0);
}
__device__ __forceinline__ bf16x8 stripsign(bf16x8 v) {
    u32x4 u = __builtin_bit_cast(u32x4, v);
    u &= 0x7fff7fffu;
    return __builtin_bit_cast(bf16x8, u);
}

// All pointers a gemm epilogue might need
struct P {
    const float* bcat; const float* pcol;
    short* qa; short* ka;           // SIGNED magnitude bf16: copysign(|v|^p, v)
    short* vt; short* kvt;
    const float* dsb; const float* dcb; const float* Ws; const float* Wc;
    short* Y; float* out;
};

// ---------------- pack weights: WcatT [2048][512] bf16 (round-6 layout) ----------------
__global__ void k_pack(const float* __restrict__ Wq, const float* __restrict__ Wk,
                       const float* __restrict__ Wvs, const float* __restrict__ Wvc,
                       const float* __restrict__ Wp,
                       const float* __restrict__ bq, const float* __restrict__ bk,
                       const float* __restrict__ bvs, const float* __restrict__ bvc,
                       const float* __restrict__ bp, const float* __restrict__ power,
                       short* __restrict__ WcatT, float* __restrict__ bcat, float* __restrict__ pcol)
{
    int i = blockIdx.x * 256 + threadIdx.x;
    int r = i >> 9, k = i & 511;
    float w;
    if (r < 512)       w = Wq[k * 512 + r];
    else if (r < 1024) w = Wk[k * 512 + (r - 512)];
    else if (r < 1536) {
        int rr = r - 1024; int h = rr >> 8; int d = rr & 255;
        w = (d < 128) ? Wvs[k * 256 + h * 128 + d] : Wvc[k * 256 + h * 128 + (d - 128)];
    } else             w = Wp[k * 512 + (r - 1536)];
    WcatT[i] = f2bf(w);

    if (i < 2048) {
        float bb;
        if (i < 512)       bb = bq[i];
        else if (i < 1024) bb = bk[i - 512];
        else if (i < 1536) {
            int rr = i - 1024; int h = rr >> 8; int d = rr & 255;
            bb = (d < 128) ? bvs[h * 128 + d] : bvc[h * 128 + (d - 128)];
        } else             bb = bp[i - 1536];
        bcat[i] = bb;
    }
    if (i < 512) pcol[i] = 1.0f + 3.0f / (1.0f + expf(-power[i]));
}

// ---------------- cast x -> bf16 ----------------
__global__ void k_cast(const float* __restrict__ x, short* __restrict__ xb)
{
    int i = blockIdx.x * 256 + threadIdx.x;
    float4 v = ((const float4*)x)[i];
    short4 s;
    s.x = f2bf(v.x); s.y = f2bf(v.y); s.z = f2bf(v.z); s.w = f2bf(v.w);
    ((short4*)xb)[i] = s;
}

// ---------------- per-row sums of k_pos / k_neg ----------------
__global__ void k_ksum(const short* __restrict__ ka,
                       float* __restrict__ kpsum, float* __restrict__ knsum)
{
    int gid = blockIdx.x * 256 + threadIdx.x;
    int gw = gid >> 6;
    int lane = gid & 63;
    short4 a4 = ((const short4*)(ka + ((size_t)gw << 8)))[lane];
    short aa[4] = {a4.x, a4.y, a4.z, a4.w};
    float sp = 0.f, sn = 0.f;
#pragma unroll
    for (int j = 0; j < 4; ++j) {
        float a = fabsf(bf2f(aa[j]));
        if (((unsigned short)aa[j] >> 15) == 0) sp += a; else sn += a;
    }
#pragma unroll
    for (int m = 1; m < 64; m <<= 1) { sp += __shfl_xor(sp, m, 64); sn += __shfl_xor(sn, m, 64); }
    if (lane == 0) { kpsum[gw] = sp; knsum[gw] = sn; }
}

// ---------------- denominators ----------------
__global__ void k_denom(const short* __restrict__ qa,
                        const float* __restrict__ kpsum, const float* __restrict__ knsum,
                        float* __restrict__ dsb, float* __restrict__ dcb)
{
    int gid = blockIdx.x * 256 + threadIdx.x;
    int gw = gid >> 6;
    int lane = gid & 63;
    int bhl = gw >> 8;
    short4 q4 = ((const short4*)(qa + ((size_t)gw << 8)))[lane];
    float4 kp4 = ((const float4*)(kpsum + ((size_t)bhl << 8)))[lane];
    float4 kn4 = ((const float4*)(knsum + ((size_t)bhl << 8)))[lane];
    short qq[4] = {q4.x, q4.y, q4.z, q4.w};
    float kp[4] = {kp4.x, kp4.y, kp4.z, kp4.w};
    float kn[4] = {kn4.x, kn4.y, kn4.z, kn4.w};
    float ss = 0.f, sc = 0.f;
#pragma unroll
    for (int j = 0; j < 4; ++j) {
        float a = fabsf(bf2f(qq[j]));
        if (((unsigned short)qq[j] >> 15) == 0) { ss += a * kp[j]; sc += a * kn[j]; }
        else                                    { ss += a * kn[j]; sc += a * kp[j]; }
    }
#pragma unroll
    for (int m = 1; m < 64; m <<= 1) { ss += __shfl_xor(ss, m, 64); sc += __shfl_xor(sc, m, 64); }
    if (lane == 0) { dsb[gw] = ss; dcb[gw] = sc; }
}

#define MODE_QK  0
#define MODE_VT  1
#define MODE_KV  2
#define MODE_CTX 3
#define MODE_OUT 4

// ---------------- NT GEMM: C[m][n] = sum_k A[m][k] * Bt[n][k] (128x128, proven structure) ----------------
// launch_bounds(256,5): 5 blocks/CU (LDS 5x32KB = 160KB exactly); VGPR cap ~102 > the 64 this
// kernel compiles to with the LDS-staged epilogue (r8's spill was the wide-store epilogue).
template <int MODE>
__launch_bounds__(256, 5)
__global__ void gemm_nt(const short* __restrict__ Ag, const short* __restrict__ Bg,
                        int K, int tilesN, P p)
{
    __shared__ __align__(16) short sm[16384];   // As = sm[0..8191], Bs = sm[8192..16383]
    short* As = sm;
    short* Bs = sm + 8192;

    // XCD-chunked bijective swizzle (all grids multiple of 8 blocks)
    const int nwg = gridDim.x * gridDim.y;
    const int s = blockIdx.y * gridDim.x + blockIdx.x;
    const int cpx = nwg >> 3;
    const int lin = (s & 7) * cpx + (s >> 3);

    int tm, tn, bhl;
    if (MODE == MODE_KV || MODE == MODE_CTX) {
        bhl = lin >> 2;
        int rem = lin & 3;
        tm = rem / tilesN; tn = rem % tilesN;
    } else {
        bhl = 0;
        tm = lin / tilesN; tn = lin % tilesN;
    }

    const short* A = Ag;
    const short* B = Bg;
    if (MODE == MODE_KV || MODE == MODE_CTX) {
        A += (size_t)bhl << 16;
        B += (size_t)bhl << 16;
    }
    constexpr bool stripA = (MODE == MODE_CTX);
    constexpr bool stripB = (MODE == MODE_KV);

    const int t = threadIdx.x;
    const int lane = t & 63;
    const int w = t >> 6;
    const int wr = w >> 1, wc = w & 1;

    f32x4 acc[4][4];
#pragma unroll
    for (int i = 0; i < 4; ++i)
#pragma unroll
        for (int j = 0; j < 4; ++j) acc[i][j] = 0.f;

    const int nkt = K >> 6;
    for (int kt = 0; kt < nkt; ++kt) {
#pragma unroll
        for (int q4i = 0; q4i < 4; ++q4i) {
            int seg = w * 4 + q4i;
            int r = seg * 8 + (lane >> 3);
            int c = (lane & 7) ^ (r & 7);
            gload_lds16(A + (size_t)(tm * 128 + r) * K + kt * 64 + c * 8, &As[seg * 512]);
            gload_lds16(B + (size_t)(tn * 128 + r) * K + kt * 64 + c * 8, &Bs[seg * 512]);
        }
        __syncthreads();
#pragma unroll
        for (int kk = 0; kk < 2; ++kk) {
            bf16x8 af[4], bfr[4];
#pragma unroll
            for (int mt = 0; mt < 4; ++mt) {
                int row = wr * 64 + mt * 16 + (lane & 15);
                int ch = kk * 4 + (lane >> 4);
                af[mt] = *(const bf16x8*)(&As[row * 64 + ((ch ^ (row & 7)) << 3)]);
                if constexpr (stripA) af[mt] = stripsign(af[mt]);
            }
#pragma unroll
            for (int nt = 0; nt < 4; ++nt) {
                int row = wc * 64 + nt * 16 + (lane & 15);
                int ch = kk * 4 + (lane >> 4);
                bfr[nt] = *(const bf16x8*)(&Bs[row * 64 + ((ch ^ (row & 7)) << 3)]);
                if constexpr (stripB) bfr[nt] = stripsign(bfr[nt]);
            }
#pragma unroll
            for (int mt = 0; mt < 4; ++mt)
#pragma unroll
                for (int nt = 0; nt < 4; ++nt)
                    acc[mt][nt] = __builtin_amdgcn_mfma_f32_16x16x32_bf16(af[mt], bfr[nt], acc[mt][nt], 0, 0, 0);
        }
        __syncthreads();
    }

    // -------- epilogue --------
    if (MODE == MODE_QK || MODE == MODE_VT) {
        // transform into LDS (bf16, swizzled 8-short granules), then coalesced 16B stores
#pragma unroll
        for (int mt = 0; mt < 4; ++mt) {
#pragma unroll
            for (int nt = 0; nt < 4; ++nt) {
#pragma unroll
                for (int r = 0; r < 4; ++r) {
                    int lrow = wr * 64 + mt * 16 + (lane >> 4) * 4 + r;
                    int lcol = wc * 64 + nt * 16 + (lane & 15);
                    float v = acc[mt][nt][r];
                    short sv;
                    if (MODE == MODE_QK) {
                        int col_g = tn * 128 + lcol;
                        v += p.bcat[col_g];
                        float pw = p.pcol[col_g & 511];
                        float a = (v != 0.0f) ? fast_exp2(pw * fast_log2(fabsf(v))) : 0.0f;
                        unsigned short sa = (unsigned short)f2bf(a);
                        sa |= (unsigned short)((__builtin_bit_cast(u32, v) >> 16) & 0x8000u);
                        sv = (short)sa;
                    } else { // MODE_VT
                        v += p.bcat[1024 + tm * 128 + lrow];
                        sv = f2bf(v);
                    }
                    int g = lcol >> 3;
                    sm[lrow * 128 + ((g ^ (lrow & 7)) << 3) + (lcol & 7)] = sv;
                }
            }
        }
        __syncthreads();
#pragma unroll
        for (int i = 0; i < 8; ++i) {
            int slot = i * 256 + t;
            int lrow = slot >> 4;
            int g = slot & 15;
            bf16x8 val = *(const bf16x8*)&sm[lrow * 128 + ((g ^ (lrow & 7)) << 3)];
            if (MODE == MODE_QK) {
                int row_g = tm * 128 + lrow;
                int col0 = tn * 128 + g * 8;
                int bl = row_g >> 8, n = row_g & 255;
                int h = (col0 >> 8) & 1;
                short* dst = (col0 < 512) ? p.qa : p.ka;
                *(bf16x8*)(dst + (((size_t)((bl * 2 + h) * 256 + n)) << 8) + (col0 & 255)) = val;
            } else {
                int d_g = tm * 128 + lrow;
                int col0 = tn * 128 + g * 8;
                int h = d_g >> 8, d = d_g & 255;
                int bl = col0 >> 8, n0 = col0 & 255;
                *(bf16x8*)(p.vt + (((size_t)((bl * 2 + h) * 256 + d)) << 8) + n0) = val;
            }
        }
    } else if (MODE == MODE_OUT) {
        float* smf = (float*)sm;
#pragma unroll
        for (int half = 0; half < 2; ++half) {
            if (wr == half) {
#pragma unroll
                for (int mt = 0; mt < 4; ++mt) {
#pragma unroll
                    for (int nt = 0; nt < 4; ++nt) {
#pragma unroll
                        for (int r = 0; r < 4; ++r) {
                            int lrow = mt * 16 + (lane >> 4) * 4 + r;
                            int lcol = wc * 64 + nt * 16 + (lane & 15);
                            float v = acc[mt][nt][r] + p.bcat[1536 + tn * 128 + lcol];
                            int g = lcol >> 2;
                            smf[lrow * 128 + ((g ^ (lrow & 7)) << 2) + (lcol & 3)] = v;
                        }
                    }
                }
            }
            __syncthreads();
#pragma unroll
            for (int i = 0; i < 8; ++i) {
                int slot = i * 256 + t;
                int lrow = slot >> 5;
                int g = slot & 31;
                float4 val = *(const float4*)&smf[lrow * 128 + ((g ^ (lrow & 7)) << 2)];
                int row_g = tm * 128 + half * 64 + lrow;
                *(float4*)(p.out + ((size_t)row_g << 9) + tn * 128 + g * 4) = val;
            }
            __syncthreads();
        }
    } else {
        // KV / CTX: LDS-staged coalesced bf16 stores
#pragma unroll
        for (int mt = 0; mt < 4; ++mt) {
#pragma unroll
            for (int nt = 0; nt < 4; ++nt) {
#pragma unroll
                for (int r = 0; r < 4; ++r) {
                    int lrow = wr * 64 + mt * 16 + (lane >> 4) * 4 + r;
                    int lcol = wc * 64 + nt * 16 + (lane & 15);
                    float v = acc[mt][nt][r];
                    short sv;
                    if (MODE == MODE_KV) {
                        sv = f2bf(v);
                    } else { // MODE_CTX
                        int n = tm * 128 + lrow, d = tn * 128 + lcol;
                        float den = ((d < 128) ? p.dsb : p.dcb)[bhl * 256 + n] + 1e-6f;
                        float wgt = (d < 128) ? p.Ws[n * 128 + d] : p.Wc[n * 128 + (d - 128)];
                        sv = f2bf(v / den * wgt);
                    }
                    int g = lcol >> 3;
                    sm[lrow * 128 + ((g ^ (lrow & 7)) << 3) + (lcol & 7)] = sv;
                }
            }
        }
        __syncthreads();
#pragma unroll
        for (int i = 0; i < 8; ++i) {
            int slot = i * 256 + t;
            int lrow = slot >> 4;
            int g = slot & 15;
            bf16x8 val = *(const bf16x8*)&sm[lrow * 128 + ((g ^ (lrow & 7)) << 3)];
            int row = tm * 128 + lrow;
            int col0 = tn * 128 + g * 8;
            if (MODE == MODE_KV) {
                *(bf16x8*)(p.kvt + ((size_t)bhl << 16) + (row << 8) + col0) = val;
            } else {
                int bl = bhl >> 1, h = bhl & 1;
                *(bf16x8*)(p.Y + ((size_t)(bl * 256 + row) << 9) + h * 256 + col0) = val;
            }
        }
    }
}

extern "C" void kernel_launch(void* const* d_in, const int* in_sizes, int n_in,
                              void* d_out, int out_size, void* d_ws, size_t ws_size,
                              hipStream_t stream)
{
    const float* x     = (const float*)d_in[0];
    const float* Wq    = (const float*)d_in[1];
    const float* bq    = (const float*)d_in[2];
    const float* Wk    = (const float*)d_in[3];
    const float* bk    = (const float*)d_in[4];
    const float* Wvs   = (const float*)d_in[5];
    const float* bvs   = (const float*)d_in[6];
    const float* Wvc   = (const float*)d_in[7];
    const float* bvc   = (const float*)d_in[8];
    const float* power = (const float*)d_in[9];
    const float* Ws    = (const float*)d_in[10];
    const float* Wc    = (const float*)d_in[11];
    const float* Wp    = (const float*)d_in[12];
    const float* bp    = (const float*)d_in[13];
    (void)in_sizes; (void)n_in; (void)out_size; (void)ws_size;

    char* ws = (char*)d_ws;
    size_t off = 0;
    auto alloc = [&](size_t bytes) { void* pp = ws + off; off += (bytes + 255) & ~(size_t)255; return pp; };
    short* Wcat = (short*)alloc(2097152);           // [2048][512] bf16
    float* bcat = (float*)alloc(8192);
    float* pcol = (float*)alloc(2048);
    short* xb   = (short*)alloc(33554432);          // [32768][512] bf16; reused as Y by CTX
    short* qa   = (short*)alloc(33554432);          // [256 bhl][256 n][256] signed bf16
    short* ka   = (short*)alloc(33554432);
    short* vt   = (short*)alloc(33554432);          // [256 bhl][256 d][256 n]
    short* kvt  = (short*)alloc(33554432);
    float* kpsum= (float*)alloc(262144);
    float* knsum= (float*)alloc(262144);
    float* dsb  = (float*)alloc(262144);
    float* dcb  = (float*)alloc(262144);

    P p{};
    p.bcat = bcat; p.pcol = pcol;
    p.qa = qa; p.ka = ka;
    p.vt = vt; p.kvt = kvt;
    p.dsb = dsb; p.dcb = dcb; p.Ws = Ws; p.Wc = Wc;
    p.Y = xb; p.out = nullptr;                      // Y overwrites xb (safe: CTX after VT)

    k_pack<<<4096, 256, 0, stream>>>(Wq, Wk, Wvs, Wvc, Wp, bq, bk, bvs, bvc, bp, power, Wcat, bcat, pcol);

    k_cast<<<16384, 256, 0, stream>>>(x, xb);

    // Q/K projection + power transform (signed-magnitude bf16): M=32768, N=1024
    gemm_nt<MODE_QK><<<dim3(2048, 1), 256, 0, stream>>>(xb, Wcat, 512, 8, p);

    // V projection, produced transposed: vt[bhl][d][n]
    gemm_nt<MODE_VT><<<dim3(1024, 1), 256, 0, stream>>>(Wcat + 1024 * 512, xb, 512, 256, p);

    // kvT[bhl][d][n] = sum_j vt[d][j] * |ka[n][j]|
    gemm_nt<MODE_KV><<<dim3(4, 256), 256, 0, stream>>>(vt, ka, 256, 2, p);

    k_ksum<<<16384, 256, 0, stream>>>(ka, kpsum, knsum);
    k_denom<<<16384, 256, 0, stream>>>(qa, kpsum, knsum, dsb, dcb);

    // ctx[n][d] = sum_i |qa[n][i]|*kvT[d][i] -> Y (=xb)
    gemm_nt<MODE_CTX><<<dim3(4, 256), 256, 0, stream>>>(qa, kvt, 256, 2, p);

    // out = Y @ Wp + bp (fp32): M=32768, N=512
    P po = p;
    po.out = (float*)d_out;
    gemm_nt<MODE_OUT><<<dim3(1024, 1), 256, 0, stream>>>(xb, Wcat + 1536 * 512, 512, 4, po);
}

// Round 18
// 203.650 us; speedup vs baseline: 2.1100x; 2.1100x over previous
//
#include <hip/hip_runtime.h>
#include <hip/hip_bf16.h>
#include <math.h>

typedef unsigned int u32;
typedef short bf16x8 __attribute__((ext_vector_type(8)));
typedef float f32x4 __attribute__((ext_vector_type(4)));
typedef u32 u32x4 __attribute__((ext_vector_type(4)));

__device__ __forceinline__ float bf2f(short s) {
    u32 u = ((u32)(unsigned short)s) << 16;
    return __builtin_bit_cast(float, u);
}
__device__ __forceinline__ short f2bf(float f) {
    u32 u = __builtin_bit_cast(u32, f);
    u32 r = u + 0x7fffu + ((u >> 16) & 1u);
    return (short)(r >> 16);
}
__device__ __forceinline__ float fast_log2(float x) {
    float r; asm volatile("v_log_f32 %0, %1" : "=v"(r) : "v"(x)); return r;
}
__device__ __forceinline__ float fast_exp2(float x) {
    float r; asm volatile("v_exp_f32 %0, %1" : "=v"(r) : "v"(x)); return r;
}
// async global->LDS, 16B per lane; lds base must be wave-uniform
__device__ __forceinline__ void gload_lds16(const short* g, short* lds) {
    __builtin_amdgcn_global_load_lds(
        (const __attribute__((address_space(1))) u32*)g,
        (__attribute__((address_space(3))) u32*)lds, 16, 0, 0);
}
__device__ __forceinline__ bf16x8 stripsign(bf16x8 v) {
    u32x4 u = __builtin_bit_cast(u32x4, v);
    u &= 0x7fff7fffu;
    return __builtin_bit_cast(bf16x8, u);
}

// All pointers a gemm epilogue might need
struct P {
    const float* bcat; const float* pcol;
    short* qa; short* ka;           // SIGNED magnitude bf16: copysign(|v|^p, v)
    short* vt; short* kvt;
    const float* dsb; const float* dcb; const float* Ws; const float* Wc;
    short* Y; float* out;
};

// ---------------- merged: cast x->bf16 (blocks 0..16383) + pack weights (16384..20479) ----------------
__global__ void k_cast_pack(const float* __restrict__ x, short* __restrict__ xb,
                            const float* __restrict__ Wq, const float* __restrict__ Wk,
                            const float* __restrict__ Wvs, const float* __restrict__ Wvc,
                            const float* __restrict__ Wp,
                            const float* __restrict__ bq, const float* __restrict__ bk,
                            const float* __restrict__ bvs, const float* __restrict__ bvc,
                            const float* __restrict__ bp, const float* __restrict__ power,
                            short* __restrict__ WcatT, float* __restrict__ bcat, float* __restrict__ pcol)
{
    int b = blockIdx.x;
    if (b < 16384) {
        int i = b * 256 + threadIdx.x;
        float4 v = ((const float4*)x)[i];
        short4 s;
        s.x = f2bf(v.x); s.y = f2bf(v.y); s.z = f2bf(v.z); s.w = f2bf(v.w);
        ((short4*)xb)[i] = s;
    } else {
        int i = (b - 16384) * 256 + threadIdx.x;      // 0 .. 2048*512-1
        int r = i >> 9, k = i & 511;
        float w;
        if (r < 512)       w = Wq[k * 512 + r];
        else if (r < 1024) w = Wk[k * 512 + (r - 512)];
        else if (r < 1536) {
            int rr = r - 1024; int h = rr >> 8; int d = rr & 255;
            w = (d < 128) ? Wvs[k * 256 + h * 128 + d] : Wvc[k * 256 + h * 128 + (d - 128)];
        } else             w = Wp[k * 512 + (r - 1536)];
        WcatT[i] = f2bf(w);

        if (i < 2048) {
            float bb;
            if (i < 512)       bb = bq[i];
            else if (i < 1024) bb = bk[i - 512];
            else if (i < 1536) {
                int rr = i - 1024; int h = rr >> 8; int d = rr & 255;
                bb = (d < 128) ? bvs[h * 128 + d] : bvc[h * 128 + (d - 128)];
            } else             bb = bp[i - 1536];
            bcat[i] = bb;
        }
        if (i < 512) pcol[i] = 1.0f + 3.0f / (1.0f + expf(-power[i]));
    }
}

// ---------------- per-row sums of k_pos / k_neg ----------------
__global__ void k_ksum(const short* __restrict__ ka,
                       float* __restrict__ kpsum, float* __restrict__ knsum)
{
    int gid = blockIdx.x * 256 + threadIdx.x;
    int gw = gid >> 6;
    int lane = gid & 63;
    short4 a4 = ((const short4*)(ka + ((size_t)gw << 8)))[lane];
    short aa[4] = {a4.x, a4.y, a4.z, a4.w};
    float sp = 0.f, sn = 0.f;
#pragma unroll
    for (int j = 0; j < 4; ++j) {
        float a = fabsf(bf2f(aa[j]));
        if (((unsigned short)aa[j] >> 15) == 0) sp += a; else sn += a;
    }
#pragma unroll
    for (int m = 1; m < 64; m <<= 1) { sp += __shfl_xor(sp, m, 64); sn += __shfl_xor(sn, m, 64); }
    if (lane == 0) { kpsum[gw] = sp; knsum[gw] = sn; }
}

// ---------------- denominators ----------------
__global__ void k_denom(const short* __restrict__ qa,
                        const float* __restrict__ kpsum, const float* __restrict__ knsum,
                        float* __restrict__ dsb, float* __restrict__ dcb)
{
    int gid = blockIdx.x * 256 + threadIdx.x;
    int gw = gid >> 6;
    int lane = gid & 63;
    int bhl = gw >> 8;
    short4 q4 = ((const short4*)(qa + ((size_t)gw << 8)))[lane];
    float4 kp4 = ((const float4*)(kpsum + ((size_t)bhl << 8)))[lane];
    float4 kn4 = ((const float4*)(knsum + ((size_t)bhl << 8)))[lane];
    short qq[4] = {q4.x, q4.y, q4.z, q4.w};
    float kp[4] = {kp4.x, kp4.y, kp4.z, kp4.w};
    float kn[4] = {kn4.x, kn4.y, kn4.z, kn4.w};
    float ss = 0.f, sc = 0.f;
#pragma unroll
    for (int j = 0; j < 4; ++j) {
        float a = fabsf(bf2f(qq[j]));
        if (((unsigned short)qq[j] >> 15) == 0) { ss += a * kp[j]; sc += a * kn[j]; }
        else                                    { ss += a * kn[j]; sc += a * kp[j]; }
    }
#pragma unroll
    for (int m = 1; m < 64; m <<= 1) { ss += __shfl_xor(ss, m, 64); sc += __shfl_xor(sc, m, 64); }
    if (lane == 0) { dsb[gw] = ss; dcb[gw] = sc; }
}

#define MODE_QK  0
#define MODE_VT  1
#define MODE_KV  2
#define MODE_CTX 3
#define MODE_OUT 4

// ---------------- NT GEMM: C[m][n] = sum_k A[m][k] * Bt[n][k] (128x128, proven structure) ----------------
// (256,4): NEVER raise to 5 — forces VGPR below the ~64 this kernel needs -> scratch spill (r8, r17).
template <int MODE>
__launch_bounds__(256, 4)
__global__ void gemm_nt(const short* __restrict__ Ag, const short* __restrict__ Bg,
                        int K, int tilesN, P p)
{
    __shared__ __align__(16) short sm[16384];   // As = sm[0..8191], Bs = sm[8192..16383]
    short* As = sm;
    short* Bs = sm + 8192;

    // XCD-chunked bijective swizzle (all grids multiple of 8 blocks)
    const int nwg = gridDim.x * gridDim.y;
    const int s = blockIdx.y * gridDim.x + blockIdx.x;
    const int cpx = nwg >> 3;
    const int lin = (s & 7) * cpx + (s >> 3);

    int tm, tn, bhl;
    if (MODE == MODE_KV || MODE == MODE_CTX) {
        bhl = lin >> 2;
        int rem = lin & 3;
        tm = rem / tilesN; tn = rem % tilesN;
    } else {
        bhl = 0;
        tm = lin / tilesN; tn = lin % tilesN;
    }

    const short* A = Ag;
    const short* B = Bg;
    if (MODE == MODE_KV || MODE == MODE_CTX) {
        A += (size_t)bhl << 16;
        B += (size_t)bhl << 16;
    }
    constexpr bool stripA = (MODE == MODE_CTX);
    constexpr bool stripB = (MODE == MODE_KV);

    const int t = threadIdx.x;
    const int lane = t & 63;
    const int w = t >> 6;
    const int wr = w >> 1, wc = w & 1;

    f32x4 acc[4][4];
#pragma unroll
    for (int i = 0; i < 4; ++i)
#pragma unroll
        for (int j = 0; j < 4; ++j) acc[i][j] = 0.f;

    const int nkt = K >> 6;
    for (int kt = 0; kt < nkt; ++kt) {
#pragma unroll
        for (int q4i = 0; q4i < 4; ++q4i) {
            int seg = w * 4 + q4i;
            int r = seg * 8 + (lane >> 3);
            int c = (lane & 7) ^ (r & 7);
            gload_lds16(A + (size_t)(tm * 128 + r) * K + kt * 64 + c * 8, &As[seg * 512]);
            gload_lds16(B + (size_t)(tn * 128 + r) * K + kt * 64 + c * 8, &Bs[seg * 512]);
        }
        __syncthreads();
#pragma unroll
        for (int kk = 0; kk < 2; ++kk) {
            bf16x8 af[4], bfr[4];
#pragma unroll
            for (int mt = 0; mt < 4; ++mt) {
                int row = wr * 64 + mt * 16 + (lane & 15);
                int ch = kk * 4 + (lane >> 4);
                af[mt] = *(const bf16x8*)(&As[row * 64 + ((ch ^ (row & 7)) << 3)]);
                if constexpr (stripA) af[mt] = stripsign(af[mt]);
            }
#pragma unroll
            for (int nt = 0; nt < 4; ++nt) {
                int row = wc * 64 + nt * 16 + (lane & 15);
                int ch = kk * 4 + (lane >> 4);
                bfr[nt] = *(const bf16x8*)(&Bs[row * 64 + ((ch ^ (row & 7)) << 3)]);
                if constexpr (stripB) bfr[nt] = stripsign(bfr[nt]);
            }
#pragma unroll
            for (int mt = 0; mt < 4; ++mt)
#pragma unroll
                for (int nt = 0; nt < 4; ++nt)
                    acc[mt][nt] = __builtin_amdgcn_mfma_f32_16x16x32_bf16(af[mt], bfr[nt], acc[mt][nt], 0, 0, 0);
        }
        __syncthreads();
    }

    // -------- epilogue --------
    if (MODE == MODE_QK || MODE == MODE_VT) {
        // transform into LDS (bf16, swizzled 8-short granules), then coalesced 16B stores
#pragma unroll
        for (int mt = 0; mt < 4; ++mt) {
#pragma unroll
            for (int nt = 0; nt < 4; ++nt) {
#pragma unroll
                for (int r = 0; r < 4; ++r) {
                    int lrow = wr * 64 + mt * 16 + (lane >> 4) * 4 + r;
                    int lcol = wc * 64 + nt * 16 + (lane & 15);
                    float v = acc[mt][nt][r];
                    short sv;
                    if (MODE == MODE_QK) {
                        int col_g = tn * 128 + lcol;
                        v += p.bcat[col_g];
                        float pw = p.pcol[col_g & 511];
                        float a = (v != 0.0f) ? fast_exp2(pw * fast_log2(fabsf(v))) : 0.0f;
                        unsigned short sa = (unsigned short)f2bf(a);
                        sa |= (unsigned short)((__builtin_bit_cast(u32, v) >> 16) & 0x8000u);
                        sv = (short)sa;
                    } else { // MODE_VT
                        v += p.bcat[1024 + tm * 128 + lrow];
                        sv = f2bf(v);
                    }
                    int g = lcol >> 3;
                    sm[lrow * 128 + ((g ^ (lrow & 7)) << 3) + (lcol & 7)] = sv;
                }
            }
        }
        __syncthreads();
#pragma unroll
        for (int i = 0; i < 8; ++i) {
            int slot = i * 256 + t;
            int lrow = slot >> 4;
            int g = slot & 15;
            bf16x8 val = *(const bf16x8*)&sm[lrow * 128 + ((g ^ (lrow & 7)) << 3)];
            if (MODE == MODE_QK) {
                int row_g = tm * 128 + lrow;
                int col0 = tn * 128 + g * 8;
                int bl = row_g >> 8, n = row_g & 255;
                int h = (col0 >> 8) & 1;
                short* dst = (col0 < 512) ? p.qa : p.ka;
                *(bf16x8*)(dst + (((size_t)((bl * 2 + h) * 256 + n)) << 8) + (col0 & 255)) = val;
            } else {
                int d_g = tm * 128 + lrow;
                int col0 = tn * 128 + g * 8;
                int h = d_g >> 8, d = d_g & 255;
                int bl = col0 >> 8, n0 = col0 & 255;
                *(bf16x8*)(p.vt + (((size_t)((bl * 2 + h) * 256 + d)) << 8) + n0) = val;
            }
        }
    } else if (MODE == MODE_OUT) {
        float* smf = (float*)sm;
#pragma unroll
        for (int half = 0; half < 2; ++half) {
            if (wr == half) {
#pragma unroll
                for (int mt = 0; mt < 4; ++mt) {
#pragma unroll
                    for (int nt = 0; nt < 4; ++nt) {
#pragma unroll
                        for (int r = 0; r < 4; ++r) {
                            int lrow = mt * 16 + (lane >> 4) * 4 + r;
                            int lcol = wc * 64 + nt * 16 + (lane & 15);
                            float v = acc[mt][nt][r] + p.bcat[1536 + tn * 128 + lcol];
                            int g = lcol >> 2;
                            smf[lrow * 128 + ((g ^ (lrow & 7)) << 2) + (lcol & 3)] = v;
                        }
                    }
                }
            }
            __syncthreads();
#pragma unroll
            for (int i = 0; i < 8; ++i) {
                int slot = i * 256 + t;
                int lrow = slot >> 5;
                int g = slot & 31;
                float4 val = *(const float4*)&smf[lrow * 128 + ((g ^ (lrow & 7)) << 2)];
                int row_g = tm * 128 + half * 64 + lrow;
                *(float4*)(p.out + ((size_t)row_g << 9) + tn * 128 + g * 4) = val;
            }
            __syncthreads();
        }
    } else {
        // KV / CTX: LDS-staged coalesced bf16 stores
#pragma unroll
        for (int mt = 0; mt < 4; ++mt) {
#pragma unroll
            for (int nt = 0; nt < 4; ++nt) {
#pragma unroll
                for (int r = 0; r < 4; ++r) {
                    int lrow = wr * 64 + mt * 16 + (lane >> 4) * 4 + r;
                    int lcol = wc * 64 + nt * 16 + (lane & 15);
                    float v = acc[mt][nt][r];
                    short sv;
                    if (MODE == MODE_KV) {
                        sv = f2bf(v);
                    } else { // MODE_CTX
                        int n = tm * 128 + lrow, d = tn * 128 + lcol;
                        float den = ((d < 128) ? p.dsb : p.dcb)[bhl * 256 + n] + 1e-6f;
                        float wgt = (d < 128) ? p.Ws[n * 128 + d] : p.Wc[n * 128 + (d - 128)];
                        sv = f2bf(v / den * wgt);
                    }
                    int g = lcol >> 3;
                    sm[lrow * 128 + ((g ^ (lrow & 7)) << 3) + (lcol & 7)] = sv;
                }
            }
        }
        __syncthreads();
#pragma unroll
        for (int i = 0; i < 8; ++i) {
            int slot = i * 256 + t;
            int lrow = slot >> 4;
            int g = slot & 15;
            bf16x8 val = *(const bf16x8*)&sm[lrow * 128 + ((g ^ (lrow & 7)) << 3)];
            int row = tm * 128 + lrow;
            int col0 = tn * 128 + g * 8;
            if (MODE == MODE_KV) {
                *(bf16x8*)(p.kvt + ((size_t)bhl << 16) + (row << 8) + col0) = val;
            } else {
                int bl = bhl >> 1, h = bhl & 1;
                *(bf16x8*)(p.Y + ((size_t)(bl * 256 + row) << 9) + h * 256 + col0) = val;
            }
        }
    }
}

extern "C" void kernel_launch(void* const* d_in, const int* in_sizes, int n_in,
                              void* d_out, int out_size, void* d_ws, size_t ws_size,
                              hipStream_t stream)
{
    const float* x     = (const float*)d_in[0];
    const float* Wq    = (const float*)d_in[1];
    const float* bq    = (const float*)d_in[2];
    const float* Wk    = (const float*)d_in[3];
    const float* bk    = (const float*)d_in[4];
    const float* Wvs   = (const float*)d_in[5];
    const float* bvs   = (const float*)d_in[6];
    const float* Wvc   = (const float*)d_in[7];
    const float* bvc   = (const float*)d_in[8];
    const float* power = (const float*)d_in[9];
    const float* Ws    = (const float*)d_in[10];
    const float* Wc    = (const float*)d_in[11];
    const float* Wp    = (const float*)d_in[12];
    const float* bp    = (const float*)d_in[13];
    (void)in_sizes; (void)n_in; (void)out_size; (void)ws_size;

    char* ws = (char*)d_ws;
    size_t off = 0;
    auto alloc = [&](size_t bytes) { void* pp = ws + off; off += (bytes + 255) & ~(size_t)255; return pp; };
    short* Wcat = (short*)alloc(2097152);           // [2048][512] bf16
    float* bcat = (float*)alloc(8192);
    float* pcol = (float*)alloc(2048);
    short* xb   = (short*)alloc(33554432);          // [32768][512] bf16; reused as Y by CTX
    short* qa   = (short*)alloc(33554432);          // [256 bhl][256 n][256] signed bf16
    short* ka   = (short*)alloc(33554432);
    short* vt   = (short*)alloc(33554432);          // [256 bhl][256 d][256 n]
    short* kvt  = (short*)alloc(33554432);
    float* kpsum= (float*)alloc(262144);
    float* knsum= (float*)alloc(262144);
    float* dsb  = (float*)alloc(262144);
    float* dcb  = (float*)alloc(262144);

    P p{};
    p.bcat = bcat; p.pcol = pcol;
    p.qa = qa; p.ka = ka;
    p.vt = vt; p.kvt = kvt;
    p.dsb = dsb; p.dcb = dcb; p.Ws = Ws; p.Wc = Wc;
    p.Y = xb; p.out = nullptr;                      // Y overwrites xb (safe: CTX after VT)

    // cast + pack merged (independent writes, no LDS)
    k_cast_pack<<<20480, 256, 0, stream>>>(x, xb, Wq, Wk, Wvs, Wvc, Wp,
                                           bq, bk, bvs, bvc, bp, power, Wcat, bcat, pcol);

    // Q/K projection + power transform (signed-magnitude bf16): M=32768, N=1024
    gemm_nt<MODE_QK><<<dim3(2048, 1), 256, 0, stream>>>(xb, Wcat, 512, 8, p);

    // V projection, produced transposed: vt[bhl][d][n]
    gemm_nt<MODE_VT><<<dim3(1024, 1), 256, 0, stream>>>(Wcat + 1024 * 512, xb, 512, 256, p);

    // kvT[bhl][d][n] = sum_j vt[d][j] * |ka[n][j]|
    gemm_nt<MODE_KV><<<dim3(4, 256), 256, 0, stream>>>(vt, ka, 256, 2, p);

    k_ksum<<<16384, 256, 0, stream>>>(ka, kpsum, knsum);
    k_denom<<<16384, 256, 0, stream>>>(qa, kpsum, knsum, dsb, dcb);

    // ctx[n][d] = sum_i |qa[n][i]|*kvT[d][i] -> Y (=xb)
    gemm_nt<MODE_CTX><<<dim3(4, 256), 256, 0, stream>>>(qa, kvt, 256, 2, p);

    // out = Y @ Wp + bp (fp32): M=32768, N=512
    P po = p;
    po.out = (float*)d_out;
    gemm_nt<MODE_OUT><<<dim3(1024, 1), 256, 0, stream>>>(xb, Wcat + 1536 * 512, 512, 4, po);
}